// Round 9
// baseline (103.934 us; speedup 1.0000x reference)
//
#include <hip/hip_runtime.h>
#include <math.h>

#define VOCAB 100000
#define EMBED 128
#define BATCH 16384
#define NPOS 10
#define NNEG 50
#define NLAB 60
#define NSLICE 8
#define SLICE_ROWS (VOCAB / NSLICE)   // 12500 rows * 256 B bf16 = 3.2 MB -> fits 4 MB XCD L2
#define NCHUNK (BATCH / 8)            // 2048 chunks of 8 batch elements
#define BUCKET_CAP 128                // mean 60, sigma 7.25 -> 9.4 sigma headroom

// ---- ws layout (bytes) ----
#define WS_TABLE 0u                         // 100000*128*2 = 25,600,000
#define WS_CBUF  25600000u                  // 16384*64*4   =  4,194,304 (bf16 centers)
#define WS_SLAB  (WS_CBUF + 4194304u)       // 16384*128*4  =  8,388,608 (bucketed entries)
#define WS_CNT   (WS_SLAB + 8388608u)       // 16384*4      =     65,536
#define WS_NEED  (WS_CNT + 65536u)          // ~38.25 MB

// ---------- helpers ----------
__device__ __forceinline__ float fast_log_sigmoid(float x) {
    const float e = __expf(-fabsf(x));
    return fminf(x, 0.0f) - __logf(1.0f + e);
}
__device__ __forceinline__ unsigned bf16rne(float f) {
    unsigned u = __float_as_uint(f);
    return (u + 0x7fffu + ((u >> 16) & 1u)) >> 16;
}
__device__ __forceinline__ unsigned pack2(float lo, float hi) {
    return bf16rne(lo) | (bf16rne(hi) << 16);
}
__device__ __forceinline__ float bl(unsigned u) { return __uint_as_float(u << 16); }
__device__ __forceinline__ float bh(unsigned u) { return __uint_as_float(u & 0xffff0000u); }
// dot of 8 bf16-pair products (both packed bf16)
__device__ __forceinline__ float dot8bb(uint4 a, uint4 b) {
    float acc =      bl(a.x) * bl(b.x);
    acc = fmaf(bh(a.x), bh(b.x), acc);
    acc = fmaf(bl(a.y), bl(b.y), acc);
    acc = fmaf(bh(a.y), bh(b.y), acc);
    acc = fmaf(bl(a.z), bl(b.z), acc);
    acc = fmaf(bh(a.z), bh(b.z), acc);
    acc = fmaf(bl(a.w), bl(b.w), acc);
    acc = fmaf(bh(a.w), bh(b.w), acc);
    return acc;
}
// f32 center halves vs packed bf16 (fallback kernel)
__device__ __forceinline__ float dot8fb(float4 x, float4 y, uint4 v) {
    float acc =      x.x * bl(v.x);
    acc = fmaf(x.y, bh(v.x), acc);
    acc = fmaf(x.z, bl(v.y), acc);
    acc = fmaf(x.w, bh(v.y), acc);
    acc = fmaf(y.x, bl(v.z), acc);
    acc = fmaf(y.y, bh(v.z), acc);
    acc = fmaf(y.z, bl(v.w), acc);
    acc = fmaf(y.w, bh(v.w), acc);
    return acc;
}

// ---------- pass 0: zero out[] and cnt[] ----------
__global__ __launch_bounds__(256) void zero_kernel(float* __restrict__ out,
                                                   unsigned* __restrict__ cnt) {
    const int i = blockIdx.x * 256 + threadIdx.x;   // 64 blocks -> 16384
    out[i] = 0.0f;
    cnt[i] = 0u;
}

// ---------- pass 1: out_embed f32 -> packed bf16 table ----------
__global__ __launch_bounds__(256) void cvt_bf16_kernel(
    const float* __restrict__ src, unsigned* __restrict__ dst, int n8)
{
    int i = blockIdx.x * 256 + threadIdx.x;
    const int stride = gridDim.x * 256;
    const float4* __restrict__ s4 = reinterpret_cast<const float4*>(src);
    uint4* __restrict__ d4 = reinterpret_cast<uint4*>(dst);
    for (; i < n8; i += stride) {
        const float4 a = s4[2 * i];
        const float4 b = s4[2 * i + 1];
        uint4 o;
        o.x = pack2(a.x, a.y);
        o.y = pack2(a.z, a.w);
        o.z = pack2(b.x, b.y);
        o.w = pack2(b.z, b.w);
        d4[i] = o;
    }
}

// ---------- pass 2: per-b prep — center cvt + bucket labels by (chunk, slice) ----------
__global__ __launch_bounds__(256) void prep_kernel(
    const int* __restrict__ input_labels,
    const int* __restrict__ pos_labels,
    const int* __restrict__ neg_labels,
    const float* __restrict__ in_embed,
    unsigned* __restrict__ cbuf,     // [B][64] packed bf16 centers
    unsigned* __restrict__ slab,     // [NCHUNK*8][BUCKET_CAP] entries
    unsigned* __restrict__ cnt)      // [NCHUNK*8]
{
    const int wave = threadIdx.x >> 6;
    const int lane = threadIdx.x & 63;
    const int b = blockIdx.x * 4 + wave;

    // center f32 -> bf16 (lane handles elems 2l, 2l+1)
    const float2 cv = *reinterpret_cast<const float2*>(
        in_embed + (unsigned)input_labels[b] * EMBED + lane * 2);
    cbuf[b * 64 + lane] = pack2(cv.x, cv.y);

    // one label per lane (lanes 60..63 inactive)
    const bool active = lane < NLAB;
    int label = 0;
    if (lane < NPOS)       label = pos_labels[b * NPOS + lane];
    else if (active)       label = neg_labels[b * NNEG + (lane - NPOS)];
    const unsigned s = (unsigned)label / SLICE_ROWS;   // 0..7

    // per-slice ballots (uniform); static-index selects (no scratch)
    unsigned long long bal[NSLICE];
    #pragma unroll
    for (int k = 0; k < NSLICE; ++k)
        bal[k] = __ballot(active && s == (unsigned)k);

    unsigned mycnt = 0;                 // lanes 0..7: count of slice `lane`
    unsigned long long mybal = 0;       // all lanes: ballot of own slice
    #pragma unroll
    for (int k = 0; k < NSLICE; ++k) {
        if (lane == k) mycnt = (unsigned)__popcll(bal[k]);
        if (s == (unsigned)k) mybal = bal[k];
    }

    const unsigned chunk8 = ((unsigned)b >> 3) * 8u;
    unsigned basev = 0;
    if (lane < NSLICE) basev = atomicAdd(&cnt[chunk8 + (unsigned)lane], mycnt);
    const unsigned base_s = (unsigned)__shfl((int)basev, (int)s);
    const unsigned rank = (unsigned)__popcll(mybal & ((1ull << lane) - 1ull));
    const unsigned idx = base_s + rank;

    if (active && idx < BUCKET_CAP)
        slab[(chunk8 + s) * BUCKET_CAP + idx] =
            ((unsigned)(b & 7) << 23) | ((unsigned)lane << 17) | (unsigned)label;
}

// ---------- pass 3: slice-local gather, one wave per (chunk, slice) ----------
__global__ __launch_bounds__(256) void main_kernel(
    const unsigned* __restrict__ slab,
    const unsigned* __restrict__ cnt,
    const unsigned* __restrict__ table,
    const unsigned* __restrict__ cbuf,
    float* __restrict__ out)
{
    const int wave = threadIdx.x >> 6;
    const int lane = threadIdx.x & 63;
    const int s = blockIdx.x & 7;                  // slice == XCD (round-robin)
    const int chunk = (blockIdx.x >> 3) * 4 + wave;
    const int g = lane >> 3, t = lane & 7;

    const unsigned bucket = (unsigned)chunk * 8u + (unsigned)s;
    unsigned count = cnt[bucket];
    if (count > BUCKET_CAP) count = BUCKET_CAP;
    if (count == 0) return;
    const unsigned sb = bucket * BUCKET_CAP;

    // preload all entries into two per-lane registers (off the critical path)
    const unsigned ent0 = slab[sb + (unsigned)lane];
    const unsigned ent1 = slab[sb + 64u + (unsigned)lane];
    const unsigned npass = (count + 7u) >> 3;

    // pass-0 entry + loads
    unsigned e = (unsigned)__shfl((int)ent0, g);
    bool v = ((unsigned)g < count);
    if (!v) e = 0u;
    unsigned co = ((unsigned)chunk * 8u + (e >> 23)) * 64u + (unsigned)(t * 4);
    unsigned ro = (e & 0x1FFFFu) * 64u + (unsigned)(t * 4);
    uint4 c0 = *reinterpret_cast<const uint4*>(cbuf + co);
    uint4 c1 = *reinterpret_cast<const uint4*>(cbuf + co + 32);
    uint4 r0 = *reinterpret_cast<const uint4*>(table + ro);
    uint4 r1 = *reinterpret_cast<const uint4*>(table + ro + 32);

    for (unsigned p = 0; p < npass; ++p) {
        unsigned en = 0u;
        bool vn = false;
        uint4 nc0, nc1, nr0, nr1;
        if (p + 1 < npass) {
            const int src = (int)(((p + 1) & 7u) * 8u) + g;
            en = (p + 1 < 8) ? (unsigned)__shfl((int)ent0, src)
                             : (unsigned)__shfl((int)ent1, src);
            vn = ((p + 1) * 8u + (unsigned)g) < count;
            if (!vn) en = 0u;
            const unsigned nco = ((unsigned)chunk * 8u + (en >> 23)) * 64u + (unsigned)(t * 4);
            const unsigned nro = (en & 0x1FFFFu) * 64u + (unsigned)(t * 4);
            nc0 = *reinterpret_cast<const uint4*>(cbuf + nco);
            nc1 = *reinterpret_cast<const uint4*>(cbuf + nco + 32);
            nr0 = *reinterpret_cast<const uint4*>(table + nro);
            nr1 = *reinterpret_cast<const uint4*>(table + nro + 32);
        }

        float acc = dot8bb(c0, r0) + dot8bb(c1, r1);
        acc += __shfl_xor(acc, 1);
        acc += __shfl_xor(acc, 2);
        acc += __shfl_xor(acc, 4);

        if (t == 0 && v) {
            const unsigned slot = (e >> 17) & 0x3Fu;
            const unsigned bl_  = e >> 23;
            const float w = (slot < NPOS) ? -1.0f : 1.0f;   // out = log_neg - log_pos
            atomicAdd(&out[(unsigned)chunk * 8u + bl_], w * fast_log_sigmoid(acc));
        }

        if (p + 1 < npass) {
            e = en; v = vn;
            c0 = nc0; c1 = nc1; r0 = nr0; r1 = nr1;
        }
    }
}

// ---------- fallback: round-6 gather (bf16 table only) ----------
__global__ __launch_bounds__(256) void skipgram_loss_bf16_kernel(
    const int* __restrict__ input_labels,
    const int* __restrict__ pos_labels,
    const int* __restrict__ neg_labels,
    const float* __restrict__ in_embed,
    const unsigned* __restrict__ out_bf,
    float* __restrict__ out)
{
    const int wave = threadIdx.x >> 6;
    const int lane = threadIdx.x & 63;
    const int b = blockIdx.x * 4 + wave;
    const int g = lane >> 3, t = lane & 7;

    const float* __restrict__ crow = in_embed + (unsigned)input_labels[b] * EMBED;
    const float4 ca = *reinterpret_cast<const float4*>(crow + t * 8);
    const float4 cb = *reinterpret_cast<const float4*>(crow + t * 8 + 4);
    const float4 cc = *reinterpret_cast<const float4*>(crow + 64 + t * 8);
    const float4 cd = *reinterpret_cast<const float4*>(crow + 64 + t * 8 + 4);

    int lab;
    if (lane < NPOS)       lab = pos_labels[b * NPOS + lane];
    else if (lane < NLAB)  lab = neg_labels[b * NNEG + (lane - NPOS)];
    else                   lab = 0;

    unsigned roff[8];
    #pragma unroll
    for (int p = 0; p < 8; ++p)
        roff[p] = (unsigned)__shfl(lab, p * 8 + g) * 64u + (unsigned)(t * 4);

    uint4 u0 = *reinterpret_cast<const uint4*>(out_bf + roff[0]);
    uint4 u1 = *reinterpret_cast<const uint4*>(out_bf + roff[0] + 32);

    float total = 0.0f;
    #pragma unroll
    for (int p = 0; p < 8; ++p) {
        uint4 n0, n1;
        if (p < 7) {
            n0 = *reinterpret_cast<const uint4*>(out_bf + roff[p + 1]);
            n1 = *reinterpret_cast<const uint4*>(out_bf + roff[p + 1] + 32);
        }
        float acc = dot8fb(ca, cb, u0) + dot8fb(cc, cd, u1);
        acc += __shfl_xor(acc, 1);
        acc += __shfl_xor(acc, 2);
        acc += __shfl_xor(acc, 4);
        const int lix = p * 8 + g;
        const float wl = (lix < NLAB) ? ((lix < NPOS) ? -1.0f : 1.0f) : 0.0f;
        total += (t == 0) ? wl * fast_log_sigmoid(acc) : 0.0f;
        if (p < 7) { u0 = n0; u1 = n1; }
    }
    total += __shfl_xor(total, 8);
    total += __shfl_xor(total, 16);
    total += __shfl_xor(total, 32);
    if (lane == 0) out[b] = total;
}

extern "C" void kernel_launch(void* const* d_in, const int* in_sizes, int n_in,
                              void* d_out, int out_size, void* d_ws, size_t ws_size,
                              hipStream_t stream) {
    const int*   input_labels = (const int*)d_in[0];
    const int*   pos_labels   = (const int*)d_in[1];
    const int*   neg_labels   = (const int*)d_in[2];
    const float* in_embed     = (const float*)d_in[3];
    const float* out_embed    = (const float*)d_in[4];
    float*       out          = (float*)d_out;

    char* ws = (char*)d_ws;
    const int n8 = VOCAB * EMBED / 8;

    if (ws_size >= WS_NEED) {
        unsigned* table = (unsigned*)(ws + WS_TABLE);
        unsigned* cbuf  = (unsigned*)(ws + WS_CBUF);
        unsigned* slab  = (unsigned*)(ws + WS_SLAB);
        unsigned* cnt   = (unsigned*)(ws + WS_CNT);

        zero_kernel<<<BATCH / 256, 256, 0, stream>>>(out, cnt);
        cvt_bf16_kernel<<<2048, 256, 0, stream>>>(out_embed, table, n8);
        prep_kernel<<<BATCH / 4, 256, 0, stream>>>(input_labels, pos_labels,
                                                   neg_labels, in_embed,
                                                   cbuf, slab, cnt);
        main_kernel<<<(NCHUNK / 4) * NSLICE, 256, 0, stream>>>(slab, cnt, table,
                                                               cbuf, out);
    } else if (ws_size >= (size_t)VOCAB * EMBED * 2) {
        unsigned* table = (unsigned*)ws;
        cvt_bf16_kernel<<<2048, 256, 0, stream>>>(out_embed, table, n8);
        skipgram_loss_bf16_kernel<<<BATCH / 4, 256, 0, stream>>>(
            input_labels, pos_labels, neg_labels, in_embed, table, out);
    }
}